// Round 1
// 907.335 us; speedup vs baseline: 1.0743x; 1.0743x over previous
//
#include <hip/hip_runtime.h>
#include <math.h>

// fMRI 3D-GNN forward, fp32. Round 4: K2 split-K 32->64 chunks (2x occupancy,
// deeper load pipeline) + K6 attention restructured to 4 targets/block
// (4x less xl re-read traffic; alpha packed [h][j][4] for float4 broadcast).

#define NB 8
#define NN 116
#define NN2 (NN*NN)          // 13456
#define KIN 6670
#define FD 16
#define KCHUNK 64
#define KSTEP 105            // ceil(6670/64)

__device__ __forceinline__ float gelu_f(float x) {
  return 0.5f * x * (1.0f + erff(x * 0.70710678118654752f));
}
__device__ __forceinline__ float lrelu(float x) {
  return fmaxf(x, 0.2f * x);
}

// ---------------- K1: x[8,6670] -> xT[6670,8] -----------------------------
__global__ void k_transpose_x(const float* __restrict__ x, float* __restrict__ xT) {
  int idx = blockIdx.x * 256 + threadIdx.x;
  if (idx >= NB * KIN) return;
  int b = idx / KIN, k = idx % KIN;
  xT[k * NB + b] = x[idx];
}

// ------------- K2: split-K big GEMM (HBM-bound: 360 MB W_gb) --------------
__global__ __launch_bounds__(256) void k_gemm_big(
    const float* __restrict__ xT, const float* __restrict__ Wg,
    float* __restrict__ partial) {
  int c0 = (blockIdx.x * 256 + threadIdx.x) * 4;
  if (c0 >= NN2) return;
  int chunk = blockIdx.y;
  int k0 = chunk * KSTEP;
  int k1 = min(k0 + KSTEP, KIN);
  float acc[NB][4];
#pragma unroll
  for (int b = 0; b < NB; b++)
#pragma unroll
    for (int c = 0; c < 4; c++) acc[b][c] = 0.f;
#pragma unroll 4
  for (int k = k0; k < k1; ++k) {
    const float4 xa = *(const float4*)(xT + k * NB);
    const float4 xb = *(const float4*)(xT + k * NB + 4);
    float4 wv = *(const float4*)(Wg + (size_t)k * NN2 + c0);
    float w[4] = {wv.x, wv.y, wv.z, wv.w};
    float xs[NB] = {xa.x, xa.y, xa.z, xa.w, xb.x, xb.y, xb.z, xb.w};
#pragma unroll
    for (int b = 0; b < NB; b++)
#pragma unroll
      for (int c = 0; c < 4; c++)
        acc[b][c] = fmaf(xs[b], w[c], acc[b][c]);
  }
#pragma unroll
  for (int b = 0; b < NB; b++)
#pragma unroll
    for (int c = 0; c < 4; c++)
      partial[((size_t)chunk * NB + b) * NN2 + c0 + c] = acc[b][c];
}

// ------------- K3: reduce partials + bias + sigmoid -> adj ----------------
__global__ void k_reduce_sigmoid(const float* __restrict__ partial,
                                 const float* __restrict__ bgb,
                                 float* __restrict__ adj) {
  int t = blockIdx.x * 256 + threadIdx.x;
  if (t >= NB * NN2) return;
  int b = t / NN2, rc = t % NN2;
  float s = bgb[rc];
#pragma unroll 8
  for (int ch = 0; ch < KCHUNK; ch++)
    s += partial[((size_t)ch * NB + b) * NN2 + rc];
  adj[t] = 1.0f / (1.0f + expf(-s));
}

// ------------- K4: row stats + FE MLP + LayerNorm -> h0 -------------------
__global__ void k_stats(const float* __restrict__ adj,
                        const float* __restrict__ feW1, const float* __restrict__ feb1,
                        const float* __restrict__ feW2, const float* __restrict__ feb2,
                        const float* __restrict__ lng, const float* __restrict__ lnb,
                        float* __restrict__ h0) {
  int b = blockIdx.x;
  int r = threadIdx.x;
  if (r >= NN) return;
  const float* row = adj + (size_t)(b * NN + r) * NN;
  float sum = 0.f;
  for (int c = 0; c < NN; c++) { float a = row[c]; sum += (a > 0.5f) ? a : 0.f; }
  float mu = sum / (float)NN;
  float ss = 0.f;
  for (int c = 0; c < NN; c++) {
    float a = row[c]; float m = (a > 0.5f) ? a : 0.f;
    float d = m - mu; ss += d * d;
  }
  float sd = sqrtf(ss / (float)(NN - 1));   // unbiased (N-1)
  float hid[8];
#pragma unroll
  for (int a = 0; a < 8; a++) {
    float z = mu * feW1[a] + sd * feW1[8 + a] + feb1[a];
    hid[a] = gelu_f(z);
  }
  float hf[FD];
  float lm = 0.f;
#pragma unroll
  for (int o = 0; o < FD; o++) {
    float z = feb2[o];
#pragma unroll
    for (int a = 0; a < 8; a++) z += hid[a] * feW2[a * FD + o];
    hf[o] = z; lm += z;
  }
  lm /= (float)FD;
  float lv = 0.f;
#pragma unroll
  for (int o = 0; o < FD; o++) { float d = hf[o] - lm; lv += d * d; }
  lv /= (float)FD;                          // biased (jnp.mean)
  float inv = 1.0f / sqrtf(lv + 1e-5f);
#pragma unroll
  for (int o = 0; o < FD; o++)
    h0[(size_t)(b * NN + r) * FD + o] = (hf[o] - lm) * inv * lng[o] + lnb[o];
}

// ------------- K5: dual GEMM  xl = A@W0+b0, xr = A@W1+b1 ------------------
// Tile 64(M) x 64(N) x 32(K); logical grid.x spans 2N columns.
#define GM 64
#define GN 64
#define GK 32
__global__ __launch_bounds__(256) void k_gemm_dual(
    const float* __restrict__ A,
    const float* __restrict__ W0, const float* __restrict__ b0,
    const float* __restrict__ W1, const float* __restrict__ b1,
    float* __restrict__ C0, float* __restrict__ C1,
    int M, int K, int N) {
  int nc = blockIdx.x * GN;
  const float* W    = (nc < N) ? W0 : W1;
  const float* bias = (nc < N) ? b0 : b1;
  float*       C    = (nc < N) ? C0 : C1;
  int n0 = (nc < N) ? nc : nc - N;
  int m0 = blockIdx.y * GM;

  __shared__ float a_s[GK][GM];       // 8 KB
  __shared__ float b_s[GK][GN + 4];   // 8.5 KB (pad kills write conflicts)
  int t = threadIdx.x;
  int tx = t & 15, ty = t >> 4;       // out: n = tx*4, m = ty*4
  float acc[4][4];
#pragma unroll
  for (int i = 0; i < 4; i++)
#pragma unroll
    for (int j = 0; j < 4; j++) acc[i][j] = 0.f;

  for (int kt = 0; kt < K; kt += GK) {
    // stage A (transposed): thread m = t&63, k8 = (t>>6)*8
    {
      int m = t & 63, k8 = (t >> 6) * 8;
      int gm = m0 + m;
      float va[8];
      if (gm < M && (kt + k8 + 8) <= K) {
        float4 v0 = *(const float4*)(A + (size_t)gm * K + kt + k8);
        float4 v1 = *(const float4*)(A + (size_t)gm * K + kt + k8 + 4);
        va[0]=v0.x; va[1]=v0.y; va[2]=v0.z; va[3]=v0.w;
        va[4]=v1.x; va[5]=v1.y; va[6]=v1.z; va[7]=v1.w;
      } else {
#pragma unroll
        for (int e = 0; e < 8; e++) {
          int gk = kt + k8 + e;
          va[e] = (gm < M && gk < K) ? A[(size_t)gm * K + gk] : 0.f;
        }
      }
#pragma unroll
      for (int e = 0; e < 8; e++) a_s[k8 + e][m] = va[e];
    }
    // stage B: thread k = t>>3, n8 = (t&7)*8
    {
      int k = t >> 3, n8 = (t & 7) * 8;
      int gk = kt + k;
      float4 w0 = make_float4(0.f,0.f,0.f,0.f), w1 = w0;
      if (gk < K) {
        const float* wp = W + (size_t)gk * N + n0 + n8;
        w0 = *(const float4*)(wp);
        w1 = *(const float4*)(wp + 4);
      }
      b_s[k][n8 + 0] = w0.x; b_s[k][n8 + 1] = w0.y;
      b_s[k][n8 + 2] = w0.z; b_s[k][n8 + 3] = w0.w;
      b_s[k][n8 + 4] = w1.x; b_s[k][n8 + 5] = w1.y;
      b_s[k][n8 + 6] = w1.z; b_s[k][n8 + 7] = w1.w;
    }
    __syncthreads();
#pragma unroll
    for (int kk = 0; kk < GK; kk++) {
      float4 av = *(const float4*)(&a_s[kk][ty << 2]);
      float4 bv = *(const float4*)(&b_s[kk][tx << 2]);
      float am[4] = {av.x, av.y, av.z, av.w};
      float bn_[4] = {bv.x, bv.y, bv.z, bv.w};
#pragma unroll
      for (int i = 0; i < 4; i++)
#pragma unroll
        for (int j = 0; j < 4; j++)
          acc[i][j] = fmaf(am[i], bn_[j], acc[i][j]);
    }
    __syncthreads();
  }
#pragma unroll
  for (int i = 0; i < 4; i++) {
    int m = m0 + (ty << 2) + i;
    if (m >= M) break;
#pragma unroll
    for (int j = 0; j < 4; j++) {
      int n = n0 + (tx << 2) + j;
      C[(size_t)m * N + n] = acc[i][j] + bias[n];
    }
  }
}

// ------------- K6: fused GATv2 scores + softmax + aggregate + gelu --------
// Round 4: 4 targets per block (grid 29 x 8). Each xl load feeds 4 targets.
// alpha stored [h][j][4] so phase 3 gets all 4 targets in one b128 broadcast.
template<int HH_, int DD_>
__global__ __launch_bounds__(256) void k_attn_aggr(
    const float* __restrict__ xl, const float* __restrict__ xr,
    const float* __restrict__ adj, const float* __restrict__ att,
    const float* __restrict__ bias, float* __restrict__ hout, int selfloop) {
  constexpr int HD = HH_ * DD_;
  __shared__ float xr_lds[4][HD];                 // 16 KB (HD=1024)
  __shared__ float att_lds[HD];                   // 4 KB
  __shared__ __align__(16) float e_lds[HH_][128][4];
  __shared__ float maskf[4][128];
  int i0 = blockIdx.x * 4, b = blockIdx.y;
  int t = threadIdx.x;

  for (int idx = t; idx < HD; idx += 256) {
    att_lds[idx] = att[idx];
#pragma unroll
    for (int ti = 0; ti < 4; ti++)
      xr_lds[ti][idx] = xr[(size_t)(b * NN + i0 + ti) * HD + idx];
  }
  if (t < 128) {
#pragma unroll
    for (int ti = 0; ti < 4; ti++) {
      int i = i0 + ti;
      bool mj = (t < NN) && ((adj[(size_t)(b * NN + t) * NN + i] > 0.5f) ||
                             (selfloop && (t == i)));
      maskf[ti][t] = mj ? 1.f : 0.f;
    }
  }
  __syncthreads();

  // ---- phase 1: raw scores e[ti][h][j], xl row loaded once per head-slice --
  int half = t >> 7;          // 0 or 1
  int j = t & 127;
  bool valid = (j < NN);
  const float* xlj = xl + (size_t)(b * NN + (valid ? j : 0)) * HD;
  if constexpr (HH_ >= 2) {
    constexpr int HHH = HH_ / 2;
#pragma unroll
    for (int hh = 0; hh < HHH; hh++) {
      int h = half * HHH + hh;
      int base = h * DD_;
      float acc[4] = {0.f, 0.f, 0.f, 0.f};
      for (int o = 0; o < DD_; o += 4) {
        float4 v  = *(const float4*)(xlj + base + o);
        float4 af = *(const float4*)(att_lds + base + o);
#pragma unroll
        for (int ti = 0; ti < 4; ti++) {
          float4 r = *(const float4*)(&xr_lds[ti][base + o]);
          float a = acc[ti];
          a = fmaf(af.x, lrelu(r.x + v.x), a);
          a = fmaf(af.y, lrelu(r.y + v.y), a);
          a = fmaf(af.z, lrelu(r.z + v.z), a);
          a = fmaf(af.w, lrelu(r.w + v.w), a);
          acc[ti] = a;
        }
      }
      if (valid)
        *(float4*)(&e_lds[h][j][0]) = make_float4(acc[0], acc[1], acc[2], acc[3]);
    }
    __syncthreads();
  } else {
    // HH==1: halves split DD, combine in LDS
    constexpr int DH = DD_ / 2;
    int base = half * DH;
    float acc[4] = {0.f, 0.f, 0.f, 0.f};
    for (int o = 0; o < DH; o += 4) {
      float4 v  = *(const float4*)(xlj + base + o);
      float4 af = *(const float4*)(att_lds + base + o);
#pragma unroll
      for (int ti = 0; ti < 4; ti++) {
        float4 r = *(const float4*)(&xr_lds[ti][base + o]);
        float a = acc[ti];
        a = fmaf(af.x, lrelu(r.x + v.x), a);
        a = fmaf(af.y, lrelu(r.y + v.y), a);
        a = fmaf(af.z, lrelu(r.z + v.z), a);
        a = fmaf(af.w, lrelu(r.w + v.w), a);
        acc[ti] = a;
      }
    }
    if (half == 0 && valid)
      *(float4*)(&e_lds[0][j][0]) = make_float4(acc[0], acc[1], acc[2], acc[3]);
    __syncthreads();
    if (half == 1 && valid) {
      float4 p = *(const float4*)(&e_lds[0][j][0]);
      p.x += acc[0]; p.y += acc[1]; p.z += acc[2]; p.w += acc[3];
      *(float4*)(&e_lds[0][j][0]) = p;
    }
    __syncthreads();
  }

  // ---- phase 2: masked softmax; wave w owns (ti,h) pairs w, w+4, ... ----
  {
    int w = t >> 6, lane = t & 63;
    for (int fh = w; fh < 4 * HH_; fh += 4) {
      int ti = fh / HH_, h = fh - ti * HH_;
      float mk0 = maskf[ti][lane], mk1 = maskf[ti][lane + 64];
      float e0 = e_lds[h][lane][ti], e1 = e_lds[h][lane + 64][ti];
      float v = fmaxf(mk0 != 0.f ? e0 : -3.0e38f,
                      mk1 != 0.f ? e1 : -3.0e38f);
#pragma unroll
      for (int o = 32; o; o >>= 1) v = fmaxf(v, __shfl_xor(v, o, 64));
      float p0 = (mk0 != 0.f) ? expf(e0 - v) : 0.f;
      float p1 = (mk1 != 0.f) ? expf(e1 - v) : 0.f;
      float s = p0 + p1;
#pragma unroll
      for (int o = 32; o; o >>= 1) s += __shfl_xor(s, o, 64);
      float inv = 1.0f / fmaxf(s, 1e-16f);
      e_lds[h][lane][ti]      = p0 * inv;
      e_lds[h][lane + 64][ti] = p1 * inv;
    }
  }
  __syncthreads();

  // ---- phase 3: out[ti][c] = sum_j alpha[ti][h(c)][j] * xl[b,j,c] ----
  constexpr int CITER = HD / 256;
  const float* xb = xl + (size_t)b * NN * HD;
  float* hb = hout + (size_t)(b * NN + i0) * HD;
#pragma unroll
  for (int it = 0; it < CITER; it++) {
    int c = t + (it << 8);
    int h = c / DD_;
    const float* xp = xb + c;
    float a0 = 0.f, a1 = 0.f, a2 = 0.f, a3 = 0.f;
#pragma unroll 4
    for (int jj = 0; jj < NN; jj++) {
      float xv = xp[(size_t)jj * HD];
      float4 al = *(const float4*)(&e_lds[h][jj][0]);   // wave-uniform broadcast
      a0 = fmaf(al.x, xv, a0);
      a1 = fmaf(al.y, xv, a1);
      a2 = fmaf(al.z, xv, a2);
      a3 = fmaf(al.w, xv, a3);
    }
    float bv = bias[c];
    hb[c]          = gelu_f(a0 + bv);
    hb[HD + c]     = gelu_f(a1 + bv);
    hb[2 * HD + c] = gelu_f(a2 + bv);
    hb[3 * HD + c] = gelu_f(a3 + bv);
  }
}

// ------------- K7: mean-pool + classifier ---------------------------------
__global__ __launch_bounds__(256) void k_classifier(
    const float* __restrict__ hfin,   // [8*116][512]
    const float* __restrict__ Wc1, const float* __restrict__ bc1,
    const float* __restrict__ bng, const float* __restrict__ bnb,
    const float* __restrict__ Wc2, const float* __restrict__ bc2,
    float* __restrict__ out) {
  __shared__ float pooled[512];
  __shared__ float cls[256];
  int b = blockIdx.x;
  int t = threadIdx.x;
#pragma unroll
  for (int r = 0; r < 2; r++) {
    int c = t + (r << 8);
    float s = 0.f;
    for (int i = 0; i < NN; i++) s += hfin[(size_t)(b * NN + i) * 512 + c];
    pooled[c] = s / (float)NN;
  }
  __syncthreads();
  {
    int n = t;
    float acc = bc1[n];
    for (int k = 0; k < 512; k++)
      acc = fmaf(pooled[k], Wc1[k * 256 + n], acc);
    float c = acc * (1.0f / sqrtf(1.0f + 1e-5f)) * bng[n] + bnb[n];
    cls[n] = gelu_f(c);
  }
  __syncthreads();
  if (t < 128) {
    int jj = t >> 6, lane = t & 63;
    float s = 0.f;
#pragma unroll
    for (int w = 0; w < 4; w++) {
      int k = lane + (w << 6);
      s += cls[k] * Wc2[k * 2 + jj];
    }
#pragma unroll
    for (int o = 32; o; o >>= 1) s += __shfl_xor(s, o, 64);
    if (lane == 0) out[b * 2 + jj] = s + bc2[jj];
  }
}

// --------------------------------------------------------------------------
extern "C" void kernel_launch(void* const* d_in, const int* in_sizes, int n_in,
                              void* d_out, int out_size, void* d_ws, size_t ws_size,
                              hipStream_t stream) {
  const float* x    = (const float*)d_in[0];
  const float* Wgb  = (const float*)d_in[1];
  const float* bgb  = (const float*)d_in[2];
  const float* feW1 = (const float*)d_in[3];
  const float* feb1 = (const float*)d_in[4];
  const float* feW2 = (const float*)d_in[5];
  const float* feb2 = (const float*)d_in[6];
  const float* lng  = (const float*)d_in[7];
  const float* lnb  = (const float*)d_in[8];
  const float* Wl[3]   = {(const float*)d_in[9],  (const float*)d_in[15], (const float*)d_in[21]};
  const float* bl[3]   = {(const float*)d_in[10], (const float*)d_in[16], (const float*)d_in[22]};
  const float* Wr[3]   = {(const float*)d_in[11], (const float*)d_in[17], (const float*)d_in[23]};
  const float* br[3]   = {(const float*)d_in[12], (const float*)d_in[18], (const float*)d_in[24]};
  const float* att[3]  = {(const float*)d_in[13], (const float*)d_in[19], (const float*)d_in[25]};
  const float* bias[3] = {(const float*)d_in[14], (const float*)d_in[20], (const float*)d_in[26]};
  const float* Wc1 = (const float*)d_in[27];
  const float* bc1 = (const float*)d_in[28];
  const float* bng = (const float*)d_in[29];
  const float* bnb = (const float*)d_in[30];
  const float* Wc2 = (const float*)d_in[31];
  const float* bc2 = (const float*)d_in[32];

  float* ws = (float*)d_ws;
  float* xT  = ws;               // 53,360 (rounded 53,376)
  float* adj = ws + 53376;       // 107,648
  float* scratch = ws + 161024;  // overlay region
  float* partial = scratch;            // 64*8*13456 = 6,889,472 (dead after K3)
  float* hA      = scratch;            // 928*1024
  float* hB      = hA + 950272;
  float* xlbuf   = hB + 950272;
  float* xrbuf   = xlbuf + 950272;

  k_transpose_x<<<dim3((NB * KIN + 255) / 256), 256, 0, stream>>>(x, xT);
  k_gemm_big<<<dim3(14, KCHUNK), 256, 0, stream>>>(xT, Wgb, partial);
  k_reduce_sigmoid<<<dim3((NB * NN2 + 255) / 256), 256, 0, stream>>>(partial, bgb, adj);
  k_stats<<<dim3(NB), 128, 0, stream>>>(adj, feW1, feb1, feW2, feb2, lng, lnb, hA);

  dim3 ab(NN / 4, NB);   // 29 x 8, 116 = 4*29 exactly
  // ---- layer 0: 16 -> 8x128, no self loops ----
  k_gemm_dual<<<dim3(2 * 1024 / GN, 15), 256, 0, stream>>>(
      hA, Wl[0], bl[0], Wr[0], br[0], xlbuf, xrbuf, 928, 16, 1024);
  k_attn_aggr<8, 128><<<ab, 256, 0, stream>>>(xlbuf, xrbuf, adj, att[0], bias[0], hB, 0);
  // ---- layer 1: 1024 -> 4x256, self loops ----
  k_gemm_dual<<<dim3(2 * 1024 / GN, 15), 256, 0, stream>>>(
      hB, Wl[1], bl[1], Wr[1], br[1], xlbuf, xrbuf, 928, 1024, 1024);
  k_attn_aggr<4, 256><<<ab, 256, 0, stream>>>(xlbuf, xrbuf, adj, att[1], bias[1], hA, 1);
  // ---- layer 2: 1024 -> 1x512, self loops ----
  k_gemm_dual<<<dim3(2 * 512 / GN, 15), 256, 0, stream>>>(
      hA, Wl[2], bl[2], Wr[2], br[2], xlbuf, xrbuf, 928, 1024, 512);
  k_attn_aggr<1, 512><<<ab, 256, 0, stream>>>(xlbuf, xrbuf, adj, att[2], bias[2], hB, 1);

  k_classifier<<<dim3(NB), 256, 0, stream>>>(hB, Wc1, bc1, bng, bnb, Wc2, bc2,
                                             (float*)d_out);
}

// Round 2
// 895.383 us; speedup vs baseline: 1.0886x; 1.0133x over previous
//
#include <hip/hip_runtime.h>
#include <math.h>

// fMRI 3D-GNN forward, fp32. Round 5: occupancy/latency attack.
// - K6 attn: 512 threads/block (2 waves/SIMD), 4-way head-slice split.
// - K5 layer-1: 128x64 tile, 8x4/thread (LDS bytes/FMA 2.0 -> 1.5).
// - K1 removed: K2 reads x via wave-uniform scalar loads.
// All accumulation orders preserved bit-exactly vs round 4.

#define NB 8
#define NN 116
#define NN2 (NN*NN)          // 13456
#define KIN 6670
#define FD 16
#define KCHUNK 64
#define KSTEP 105            // ceil(6670/64)

__device__ __forceinline__ float gelu_f(float x) {
  return 0.5f * x * (1.0f + erff(x * 0.70710678118654752f));
}
__device__ __forceinline__ float lrelu(float x) {
  return fmaxf(x, 0.2f * x);
}

// ------------- K2: split-K big GEMM (HBM-bound: 360 MB W_gb) --------------
__global__ __launch_bounds__(256) void k_gemm_big(
    const float* __restrict__ x, const float* __restrict__ Wg,
    float* __restrict__ partial) {
  int c0 = (blockIdx.x * 256 + threadIdx.x) * 4;
  if (c0 >= NN2) return;
  int chunk = blockIdx.y;
  int k0 = chunk * KSTEP;
  int k1 = min(k0 + KSTEP, KIN);
  float acc[NB][4];
#pragma unroll
  for (int b = 0; b < NB; b++)
#pragma unroll
    for (int c = 0; c < 4; c++) acc[b][c] = 0.f;
#pragma unroll 8
  for (int k = k0; k < k1; ++k) {
    float4 wv = *(const float4*)(Wg + (size_t)k * NN2 + c0);
    float w[4] = {wv.x, wv.y, wv.z, wv.w};
    float xs[NB];
#pragma unroll
    for (int b = 0; b < NB; b++) xs[b] = x[b * KIN + k];   // wave-uniform -> s_load
#pragma unroll
    for (int b = 0; b < NB; b++)
#pragma unroll
      for (int c = 0; c < 4; c++)
        acc[b][c] = fmaf(xs[b], w[c], acc[b][c]);
  }
#pragma unroll
  for (int b = 0; b < NB; b++)
#pragma unroll
    for (int c = 0; c < 4; c++)
      partial[((size_t)chunk * NB + b) * NN2 + c0 + c] = acc[b][c];
}

// ------------- K3: reduce partials + bias + sigmoid -> adj ----------------
__global__ void k_reduce_sigmoid(const float* __restrict__ partial,
                                 const float* __restrict__ bgb,
                                 float* __restrict__ adj) {
  int t = blockIdx.x * 256 + threadIdx.x;
  if (t >= NB * NN2) return;
  int b = t / NN2, rc = t % NN2;
  float s = bgb[rc];
#pragma unroll 8
  for (int ch = 0; ch < KCHUNK; ch++)
    s += partial[((size_t)ch * NB + b) * NN2 + rc];
  adj[t] = 1.0f / (1.0f + expf(-s));
}

// ------------- K4: row stats + FE MLP + LayerNorm -> h0 -------------------
__global__ void k_stats(const float* __restrict__ adj,
                        const float* __restrict__ feW1, const float* __restrict__ feb1,
                        const float* __restrict__ feW2, const float* __restrict__ feb2,
                        const float* __restrict__ lng, const float* __restrict__ lnb,
                        float* __restrict__ h0) {
  int b = blockIdx.x;
  int r = threadIdx.x;
  if (r >= NN) return;
  const float* row = adj + (size_t)(b * NN + r) * NN;
  float sum = 0.f;
  for (int c = 0; c < NN; c++) { float a = row[c]; sum += (a > 0.5f) ? a : 0.f; }
  float mu = sum / (float)NN;
  float ss = 0.f;
  for (int c = 0; c < NN; c++) {
    float a = row[c]; float m = (a > 0.5f) ? a : 0.f;
    float d = m - mu; ss += d * d;
  }
  float sd = sqrtf(ss / (float)(NN - 1));   // unbiased (N-1)
  float hid[8];
#pragma unroll
  for (int a = 0; a < 8; a++) {
    float z = mu * feW1[a] + sd * feW1[8 + a] + feb1[a];
    hid[a] = gelu_f(z);
  }
  float hf[FD];
  float lm = 0.f;
#pragma unroll
  for (int o = 0; o < FD; o++) {
    float z = feb2[o];
#pragma unroll
    for (int a = 0; a < 8; a++) z += hid[a] * feW2[a * FD + o];
    hf[o] = z; lm += z;
  }
  lm /= (float)FD;
  float lv = 0.f;
#pragma unroll
  for (int o = 0; o < FD; o++) { float d = hf[o] - lm; lv += d * d; }
  lv /= (float)FD;                          // biased (jnp.mean)
  float inv = 1.0f / sqrtf(lv + 1e-5f);
#pragma unroll
  for (int o = 0; o < FD; o++)
    h0[(size_t)(b * NN + r) * FD + o] = (hf[o] - lm) * inv * lng[o] + lnb[o];
}

// ------------- K5: dual GEMM  xl = A@W0+b0, xr = A@W1+b1 ------------------
// Tile GM_(=16*TM_) x 64(N) x 32(K); grid.x spans 2N columns.
#define GN 64
#define GK 32
template<int GM_, int TM_>
__global__ __launch_bounds__(256) void k_gemm_dual(
    const float* __restrict__ A,
    const float* __restrict__ W0, const float* __restrict__ b0,
    const float* __restrict__ W1, const float* __restrict__ b1,
    float* __restrict__ C0, float* __restrict__ C1,
    int M, int K, int N) {
  int nc = blockIdx.x * GN;
  const float* W    = (nc < N) ? W0 : W1;
  const float* bias = (nc < N) ? b0 : b1;
  float*       C    = (nc < N) ? C0 : C1;
  int n0 = (nc < N) ? nc : nc - N;
  int m0 = blockIdx.y * GM_;

  __shared__ float a_s[GK][GM_];      // 8 or 16 KB
  __shared__ float b_s[GK][GN + 4];   // 8.5 KB (pad kills write conflicts)
  int t = threadIdx.x;
  int tx = t & 15, ty = t >> 4;       // out: n = tx*4, m = ty*TM_
  float acc[TM_][4];
#pragma unroll
  for (int i = 0; i < TM_; i++)
#pragma unroll
    for (int j = 0; j < 4; j++) acc[i][j] = 0.f;

  constexpr int EPT = GM_ * GK / 256; // k-elems staged per thread (8 or 16)

  for (int kt = 0; kt < K; kt += GK) {
    // stage A (transposed): thread row m = t % GM_, k-range kq = (t/GM_)*EPT
    {
      int m = t & (GM_ - 1), kq = (t / GM_) * EPT;
      int gm = m0 + m;
      if (gm < M && (kt + kq + EPT) <= K) {
#pragma unroll
        for (int e = 0; e < EPT; e += 4) {
          float4 v = *(const float4*)(A + (size_t)gm * K + kt + kq + e);
          a_s[kq + e + 0][m] = v.x; a_s[kq + e + 1][m] = v.y;
          a_s[kq + e + 2][m] = v.z; a_s[kq + e + 3][m] = v.w;
        }
      } else {
#pragma unroll
        for (int e = 0; e < EPT; e++) {
          int gk = kt + kq + e;
          a_s[kq + e][m] = (gm < M && gk < K) ? A[(size_t)gm * K + gk] : 0.f;
        }
      }
    }
    // stage B: thread k = t>>3, n8 = (t&7)*8
    {
      int k = t >> 3, n8 = (t & 7) * 8;
      int gk = kt + k;
      float4 w0 = make_float4(0.f,0.f,0.f,0.f), w1 = w0;
      if (gk < K) {
        const float* wp = W + (size_t)gk * N + n0 + n8;
        w0 = *(const float4*)(wp);
        w1 = *(const float4*)(wp + 4);
      }
      b_s[k][n8 + 0] = w0.x; b_s[k][n8 + 1] = w0.y;
      b_s[k][n8 + 2] = w0.z; b_s[k][n8 + 3] = w0.w;
      b_s[k][n8 + 4] = w1.x; b_s[k][n8 + 5] = w1.y;
      b_s[k][n8 + 6] = w1.z; b_s[k][n8 + 7] = w1.w;
    }
    __syncthreads();
#pragma unroll
    for (int kk = 0; kk < GK; kk++) {
      float4 bv = *(const float4*)(&b_s[kk][tx << 2]);
      float bn_[4] = {bv.x, bv.y, bv.z, bv.w};
#pragma unroll
      for (int r = 0; r < TM_ / 4; r++) {
        float4 av = *(const float4*)(&a_s[kk][ty * TM_ + r * 4]);
        float am[4] = {av.x, av.y, av.z, av.w};
#pragma unroll
        for (int i = 0; i < 4; i++)
#pragma unroll
          for (int j = 0; j < 4; j++)
            acc[r * 4 + i][j] = fmaf(am[i], bn_[j], acc[r * 4 + i][j]);
      }
    }
    __syncthreads();
  }
#pragma unroll
  for (int i = 0; i < TM_; i++) {
    int m = m0 + ty * TM_ + i;
    if (m >= M) break;
#pragma unroll
    for (int j = 0; j < 4; j++) {
      int n = n0 + (tx << 2) + j;
      C[(size_t)m * N + n] = acc[i][j] + bias[n];
    }
  }
}

// ------------- K6: fused GATv2 scores + softmax + aggregate + gelu --------
// 4 targets per block, 512 threads (8 waves -> 2 waves/SIMD).
// Head-slices split 4-way (HH>=4, bit-exact per head); HH==1 keeps the
// exact 2-half split. alpha packed [h][j][4] for float4 broadcast.
template<int HH_, int DD_>
__global__ __launch_bounds__(512) void k_attn_aggr(
    const float* __restrict__ xl, const float* __restrict__ xr,
    const float* __restrict__ adj, const float* __restrict__ att,
    const float* __restrict__ bias, float* __restrict__ hout, int selfloop) {
  constexpr int HD = HH_ * DD_;
  __shared__ float xr_lds[4][HD];
  __shared__ float att_lds[HD];
  __shared__ __align__(16) float e_lds[HH_][128][4];
  __shared__ float maskf[4][128];
  int i0 = blockIdx.x * 4, b = blockIdx.y;
  int t = threadIdx.x;

  for (int idx = t; idx < HD; idx += 512) {
    att_lds[idx] = att[idx];
#pragma unroll
    for (int ti = 0; ti < 4; ti++)
      xr_lds[ti][idx] = xr[(size_t)(b * NN + i0 + ti) * HD + idx];
  }
  if (t < 128) {
#pragma unroll
    for (int ti = 0; ti < 4; ti++) {
      int i = i0 + ti;
      bool mj = (t < NN) && ((adj[(size_t)(b * NN + t) * NN + i] > 0.5f) ||
                             (selfloop && (t == i)));
      maskf[ti][t] = mj ? 1.f : 0.f;
    }
  }
  __syncthreads();

  // ---- phase 1: raw scores e[ti][h][j] ----
  int slice = t >> 7;         // 0..3
  int j = t & 127;
  bool valid = (j < NN);
  const float* xlj = xl + (size_t)(b * NN + (valid ? j : 0)) * HD;
  if constexpr (HH_ >= 4) {
    constexpr int HQ = HH_ / 4;
#pragma unroll
    for (int hh = 0; hh < HQ; hh++) {
      int h = slice * HQ + hh;
      int base = h * DD_;
      float acc[4] = {0.f, 0.f, 0.f, 0.f};
      for (int o = 0; o < DD_; o += 4) {
        float4 v  = *(const float4*)(xlj + base + o);
        float4 af = *(const float4*)(att_lds + base + o);
#pragma unroll
        for (int ti = 0; ti < 4; ti++) {
          float4 r = *(const float4*)(&xr_lds[ti][base + o]);
          float a = acc[ti];
          a = fmaf(af.x, lrelu(r.x + v.x), a);
          a = fmaf(af.y, lrelu(r.y + v.y), a);
          a = fmaf(af.z, lrelu(r.z + v.z), a);
          a = fmaf(af.w, lrelu(r.w + v.w), a);
          acc[ti] = a;
        }
      }
      if (valid)
        *(float4*)(&e_lds[h][j][0]) = make_float4(acc[0], acc[1], acc[2], acc[3]);
    }
    __syncthreads();
  } else {
    // HH==1: exact 2-half split (slices 2,3 idle in compute)
    constexpr int DH = DD_ / 2;
    float acc[4] = {0.f, 0.f, 0.f, 0.f};
    if (slice < 2) {
      int base = slice * DH;
      for (int o = 0; o < DH; o += 4) {
        float4 v  = *(const float4*)(xlj + base + o);
        float4 af = *(const float4*)(att_lds + base + o);
#pragma unroll
        for (int ti = 0; ti < 4; ti++) {
          float4 r = *(const float4*)(&xr_lds[ti][base + o]);
          float a = acc[ti];
          a = fmaf(af.x, lrelu(r.x + v.x), a);
          a = fmaf(af.y, lrelu(r.y + v.y), a);
          a = fmaf(af.z, lrelu(r.z + v.z), a);
          a = fmaf(af.w, lrelu(r.w + v.w), a);
          acc[ti] = a;
        }
      }
    }
    if (slice == 0 && valid)
      *(float4*)(&e_lds[0][j][0]) = make_float4(acc[0], acc[1], acc[2], acc[3]);
    __syncthreads();
    if (slice == 1 && valid) {
      float4 p = *(const float4*)(&e_lds[0][j][0]);
      p.x += acc[0]; p.y += acc[1]; p.z += acc[2]; p.w += acc[3];
      *(float4*)(&e_lds[0][j][0]) = p;
    }
    __syncthreads();
  }

  // ---- phase 2: masked softmax; wave w owns (ti,h) pairs w, w+8, ... ----
  {
    int w = t >> 6, lane = t & 63;
    for (int fh = w; fh < 4 * HH_; fh += 8) {
      int ti = fh / HH_, h = fh - ti * HH_;
      float mk0 = maskf[ti][lane], mk1 = maskf[ti][lane + 64];
      float e0 = e_lds[h][lane][ti], e1 = e_lds[h][lane + 64][ti];
      float v = fmaxf(mk0 != 0.f ? e0 : -3.0e38f,
                      mk1 != 0.f ? e1 : -3.0e38f);
#pragma unroll
      for (int o = 32; o; o >>= 1) v = fmaxf(v, __shfl_xor(v, o, 64));
      float p0 = (mk0 != 0.f) ? expf(e0 - v) : 0.f;
      float p1 = (mk1 != 0.f) ? expf(e1 - v) : 0.f;
      float s = p0 + p1;
#pragma unroll
      for (int o = 32; o; o >>= 1) s += __shfl_xor(s, o, 64);
      float inv = 1.0f / fmaxf(s, 1e-16f);
      e_lds[h][lane][ti]      = p0 * inv;
      e_lds[h][lane + 64][ti] = p1 * inv;
    }
  }
  __syncthreads();

  // ---- phase 3: out[ti][c] = sum_j alpha[ti][h(c)][j] * xl[b,j,c] ----
  constexpr int CITER = HD / 512;
  const float* xb = xl + (size_t)b * NN * HD;
  float* hb = hout + (size_t)(b * NN + i0) * HD;
#pragma unroll
  for (int it = 0; it < CITER; it++) {
    int c = t + (it << 9);
    int h = c / DD_;
    const float* xp = xb + c;
    float a0 = 0.f, a1 = 0.f, a2 = 0.f, a3 = 0.f;
#pragma unroll 4
    for (int jj = 0; jj < NN; jj++) {
      float xv = xp[(size_t)jj * HD];
      float4 al = *(const float4*)(&e_lds[h][jj][0]);   // wave-uniform broadcast
      a0 = fmaf(al.x, xv, a0);
      a1 = fmaf(al.y, xv, a1);
      a2 = fmaf(al.z, xv, a2);
      a3 = fmaf(al.w, xv, a3);
    }
    float bv = bias[c];
    hb[c]          = gelu_f(a0 + bv);
    hb[HD + c]     = gelu_f(a1 + bv);
    hb[2 * HD + c] = gelu_f(a2 + bv);
    hb[3 * HD + c] = gelu_f(a3 + bv);
  }
}

// ------------- K7: mean-pool + classifier ---------------------------------
__global__ __launch_bounds__(256) void k_classifier(
    const float* __restrict__ hfin,   // [8*116][512]
    const float* __restrict__ Wc1, const float* __restrict__ bc1,
    const float* __restrict__ bng, const float* __restrict__ bnb,
    const float* __restrict__ Wc2, const float* __restrict__ bc2,
    float* __restrict__ out) {
  __shared__ float pooled[512];
  __shared__ float cls[256];
  int b = blockIdx.x;
  int t = threadIdx.x;
#pragma unroll
  for (int r = 0; r < 2; r++) {
    int c = t + (r << 8);
    float s = 0.f;
    for (int i = 0; i < NN; i++) s += hfin[(size_t)(b * NN + i) * 512 + c];
    pooled[c] = s / (float)NN;
  }
  __syncthreads();
  {
    int n = t;
    float acc = bc1[n];
    for (int k = 0; k < 512; k++)
      acc = fmaf(pooled[k], Wc1[k * 256 + n], acc);
    float c = acc * (1.0f / sqrtf(1.0f + 1e-5f)) * bng[n] + bnb[n];
    cls[n] = gelu_f(c);
  }
  __syncthreads();
  if (t < 128) {
    int jj = t >> 6, lane = t & 63;
    float s = 0.f;
#pragma unroll
    for (int w = 0; w < 4; w++) {
      int k = lane + (w << 6);
      s += cls[k] * Wc2[k * 2 + jj];
    }
#pragma unroll
    for (int o = 32; o; o >>= 1) s += __shfl_xor(s, o, 64);
    if (lane == 0) out[b * 2 + jj] = s + bc2[jj];
  }
}

// --------------------------------------------------------------------------
extern "C" void kernel_launch(void* const* d_in, const int* in_sizes, int n_in,
                              void* d_out, int out_size, void* d_ws, size_t ws_size,
                              hipStream_t stream) {
  const float* x    = (const float*)d_in[0];
  const float* Wgb  = (const float*)d_in[1];
  const float* bgb  = (const float*)d_in[2];
  const float* feW1 = (const float*)d_in[3];
  const float* feb1 = (const float*)d_in[4];
  const float* feW2 = (const float*)d_in[5];
  const float* feb2 = (const float*)d_in[6];
  const float* lng  = (const float*)d_in[7];
  const float* lnb  = (const float*)d_in[8];
  const float* Wl[3]   = {(const float*)d_in[9],  (const float*)d_in[15], (const float*)d_in[21]};
  const float* bl[3]   = {(const float*)d_in[10], (const float*)d_in[16], (const float*)d_in[22]};
  const float* Wr[3]   = {(const float*)d_in[11], (const float*)d_in[17], (const float*)d_in[23]};
  const float* br[3]   = {(const float*)d_in[12], (const float*)d_in[18], (const float*)d_in[24]};
  const float* att[3]  = {(const float*)d_in[13], (const float*)d_in[19], (const float*)d_in[25]};
  const float* bias[3] = {(const float*)d_in[14], (const float*)d_in[20], (const float*)d_in[26]};
  const float* Wc1 = (const float*)d_in[27];
  const float* bc1 = (const float*)d_in[28];
  const float* bng = (const float*)d_in[29];
  const float* bnb = (const float*)d_in[30];
  const float* Wc2 = (const float*)d_in[31];
  const float* bc2 = (const float*)d_in[32];

  float* ws = (float*)d_ws;
  float* adj = ws + 53376;       // 107,648 floats
  float* scratch = ws + 161024;  // overlay region
  float* partial = scratch;            // 64*8*13456 = 6,889,472 (dead after K3)
  float* hA      = scratch;            // 928*1024
  float* hB      = hA + 950272;
  float* xlbuf   = hB + 950272;
  float* xrbuf   = xlbuf + 950272;

  k_gemm_big<<<dim3(14, KCHUNK), 256, 0, stream>>>(x, Wgb, partial);
  k_reduce_sigmoid<<<dim3((NB * NN2 + 255) / 256), 256, 0, stream>>>(partial, bgb, adj);
  k_stats<<<dim3(NB), 128, 0, stream>>>(adj, feW1, feb1, feW2, feb2, lng, lnb, hA);

  dim3 ab(NN / 4, NB);   // 29 x 8
  // ---- layer 0: 16 -> 8x128, no self loops ----
  k_gemm_dual<64, 4><<<dim3(2 * 1024 / GN, 15), 256, 0, stream>>>(
      hA, Wl[0], bl[0], Wr[0], br[0], xlbuf, xrbuf, 928, 16, 1024);
  k_attn_aggr<8, 128><<<ab, 512, 0, stream>>>(xlbuf, xrbuf, adj, att[0], bias[0], hB, 0);
  // ---- layer 1: 1024 -> 4x256, self loops (128x64 tile, 256 blocks) ----
  k_gemm_dual<128, 8><<<dim3(2 * 1024 / GN, 8), 256, 0, stream>>>(
      hB, Wl[1], bl[1], Wr[1], br[1], xlbuf, xrbuf, 928, 1024, 1024);
  k_attn_aggr<4, 256><<<ab, 512, 0, stream>>>(xlbuf, xrbuf, adj, att[1], bias[1], hA, 1);
  // ---- layer 2: 1024 -> 1x512, self loops ----
  k_gemm_dual<64, 4><<<dim3(2 * 512 / GN, 15), 256, 0, stream>>>(
      hA, Wl[2], bl[2], Wr[2], br[2], xlbuf, xrbuf, 928, 1024, 512);
  k_attn_aggr<1, 512><<<ab, 512, 0, stream>>>(xlbuf, xrbuf, adj, att[2], bias[2], hB, 1);

  k_classifier<<<dim3(NB), 256, 0, stream>>>(hB, Wc1, bc1, bng, bnb, Wc2, bc2,
                                             (float*)d_out);
}

// Round 3
// 858.349 us; speedup vs baseline: 1.1356x; 1.0431x over previous
//
#include <hip/hip_runtime.h>
#include <math.h>

// fMRI 3D-GNN forward, fp32. Round 6: latency-exposure attack.
// - K2: x-slice staged in LDS (kills per-iter s_load serialization).
// - K5 L1/L2: reg-staged double-buffered LDS, GM=64 (480/240 blocks ~2/CU).
// - K6 attn: 2 targets/block, grid 58x8=464 (~1.8 blocks/CU).
// All accumulation orders preserved bit-exactly.

#define NB 8
#define NN 116
#define NN2 (NN*NN)          // 13456
#define KIN 6670
#define FD 16
#define KCHUNK 64
#define KSTEP 105            // ceil(6670/64)

__device__ __forceinline__ float gelu_f(float x) {
  return 0.5f * x * (1.0f + erff(x * 0.70710678118654752f));
}
__device__ __forceinline__ float lrelu(float x) {
  return fmaxf(x, 0.2f * x);
}

// ------------- K2: split-K big GEMM (HBM-bound: 360 MB W_gb) --------------
__global__ __launch_bounds__(256) void k_gemm_big(
    const float* __restrict__ x, const float* __restrict__ Wg,
    float* __restrict__ partial) {
  __shared__ float xs_lds[KSTEP][8];   // 3.4 KB
  int t = threadIdx.x;
  int chunk = blockIdx.y;
  int k0 = chunk * KSTEP;
  for (int e = t; e < KSTEP * 8; e += 256) {
    int kk = e >> 3, bb = e & 7;
    int gk = k0 + kk;
    xs_lds[kk][bb] = (gk < KIN) ? x[bb * KIN + gk] : 0.f;
  }
  __syncthreads();
  int c0 = (blockIdx.x * 256 + t) * 4;
  if (c0 >= NN2) return;
  int k1 = min(k0 + KSTEP, KIN);
  float acc[NB][4];
#pragma unroll
  for (int b = 0; b < NB; b++)
#pragma unroll
    for (int c = 0; c < 4; c++) acc[b][c] = 0.f;
#pragma unroll 8
  for (int k = k0; k < k1; ++k) {
    float4 wv = *(const float4*)(Wg + (size_t)k * NN2 + c0);
    float4 xa = *(const float4*)(&xs_lds[k - k0][0]);   // LDS broadcast
    float4 xb = *(const float4*)(&xs_lds[k - k0][4]);
    float w[4] = {wv.x, wv.y, wv.z, wv.w};
    float xs[NB] = {xa.x, xa.y, xa.z, xa.w, xb.x, xb.y, xb.z, xb.w};
#pragma unroll
    for (int b = 0; b < NB; b++)
#pragma unroll
      for (int c = 0; c < 4; c++)
        acc[b][c] = fmaf(xs[b], w[c], acc[b][c]);
  }
#pragma unroll
  for (int b = 0; b < NB; b++)
#pragma unroll
    for (int c = 0; c < 4; c++)
      partial[((size_t)chunk * NB + b) * NN2 + c0 + c] = acc[b][c];
}

// ------------- K3: reduce partials + bias + sigmoid -> adj ----------------
__global__ void k_reduce_sigmoid(const float* __restrict__ partial,
                                 const float* __restrict__ bgb,
                                 float* __restrict__ adj) {
  int t = blockIdx.x * 256 + threadIdx.x;
  if (t >= NB * NN2) return;
  int b = t / NN2, rc = t % NN2;
  float s = bgb[rc];
#pragma unroll 8
  for (int ch = 0; ch < KCHUNK; ch++)
    s += partial[((size_t)ch * NB + b) * NN2 + rc];
  adj[t] = 1.0f / (1.0f + expf(-s));
}

// ------------- K4: row stats + FE MLP + LayerNorm -> h0 -------------------
__global__ void k_stats(const float* __restrict__ adj,
                        const float* __restrict__ feW1, const float* __restrict__ feb1,
                        const float* __restrict__ feW2, const float* __restrict__ feb2,
                        const float* __restrict__ lng, const float* __restrict__ lnb,
                        float* __restrict__ h0) {
  int b = blockIdx.x;
  int r = threadIdx.x;
  if (r >= NN) return;
  const float* row = adj + (size_t)(b * NN + r) * NN;
  float sum = 0.f;
  for (int c = 0; c < NN; c++) { float a = row[c]; sum += (a > 0.5f) ? a : 0.f; }
  float mu = sum / (float)NN;
  float ss = 0.f;
  for (int c = 0; c < NN; c++) {
    float a = row[c]; float m = (a > 0.5f) ? a : 0.f;
    float d = m - mu; ss += d * d;
  }
  float sd = sqrtf(ss / (float)(NN - 1));   // unbiased (N-1)
  float hid[8];
#pragma unroll
  for (int a = 0; a < 8; a++) {
    float z = mu * feW1[a] + sd * feW1[8 + a] + feb1[a];
    hid[a] = gelu_f(z);
  }
  float hf[FD];
  float lm = 0.f;
#pragma unroll
  for (int o = 0; o < FD; o++) {
    float z = feb2[o];
#pragma unroll
    for (int a = 0; a < 8; a++) z += hid[a] * feW2[a * FD + o];
    hf[o] = z; lm += z;
  }
  lm /= (float)FD;
  float lv = 0.f;
#pragma unroll
  for (int o = 0; o < FD; o++) { float d = hf[o] - lm; lv += d * d; }
  lv /= (float)FD;                          // biased (jnp.mean)
  float inv = 1.0f / sqrtf(lv + 1e-5f);
#pragma unroll
  for (int o = 0; o < FD; o++)
    h0[(size_t)(b * NN + r) * FD + o] = (hf[o] - lm) * inv * lng[o] + lnb[o];
}

// ------------- K5a: simple dual GEMM (layer 0, K=16) ----------------------
#define GN 64
#define GK 32
template<int GM_, int TM_>
__global__ __launch_bounds__(256) void k_gemm_dual_s(
    const float* __restrict__ A,
    const float* __restrict__ W0, const float* __restrict__ b0,
    const float* __restrict__ W1, const float* __restrict__ b1,
    float* __restrict__ C0, float* __restrict__ C1,
    int M, int K, int N) {
  int nc = blockIdx.x * GN;
  const float* W    = (nc < N) ? W0 : W1;
  const float* bias = (nc < N) ? b0 : b1;
  float*       C    = (nc < N) ? C0 : C1;
  int n0 = (nc < N) ? nc : nc - N;
  int m0 = blockIdx.y * GM_;

  __shared__ float a_s[GK][GM_];
  __shared__ float b_s[GK][GN + 4];
  int t = threadIdx.x;
  int tx = t & 15, ty = t >> 4;
  float acc[TM_][4];
#pragma unroll
  for (int i = 0; i < TM_; i++)
#pragma unroll
    for (int j = 0; j < 4; j++) acc[i][j] = 0.f;

  constexpr int EPT = GM_ * GK / 256;

  for (int kt = 0; kt < K; kt += GK) {
    {
      int m = t & (GM_ - 1), kq = (t / GM_) * EPT;
      int gm = m0 + m;
#pragma unroll
      for (int e = 0; e < EPT; e++) {
        int gk = kt + kq + e;
        a_s[kq + e][m] = (gm < M && gk < K) ? A[(size_t)gm * K + gk] : 0.f;
      }
    }
    {
      int k = t >> 3, n8 = (t & 7) * 8;
      int gk = kt + k;
      float4 w0 = make_float4(0.f,0.f,0.f,0.f), w1 = w0;
      if (gk < K) {
        const float* wp = W + (size_t)gk * N + n0 + n8;
        w0 = *(const float4*)(wp);
        w1 = *(const float4*)(wp + 4);
      }
      b_s[k][n8 + 0] = w0.x; b_s[k][n8 + 1] = w0.y;
      b_s[k][n8 + 2] = w0.z; b_s[k][n8 + 3] = w0.w;
      b_s[k][n8 + 4] = w1.x; b_s[k][n8 + 5] = w1.y;
      b_s[k][n8 + 6] = w1.z; b_s[k][n8 + 7] = w1.w;
    }
    __syncthreads();
#pragma unroll
    for (int kk = 0; kk < GK; kk++) {
      float4 bv = *(const float4*)(&b_s[kk][tx << 2]);
      float bn_[4] = {bv.x, bv.y, bv.z, bv.w};
#pragma unroll
      for (int r = 0; r < TM_ / 4; r++) {
        float4 av = *(const float4*)(&a_s[kk][ty * TM_ + r * 4]);
        float am[4] = {av.x, av.y, av.z, av.w};
#pragma unroll
        for (int i = 0; i < 4; i++)
#pragma unroll
          for (int j = 0; j < 4; j++)
            acc[r * 4 + i][j] = fmaf(am[i], bn_[j], acc[r * 4 + i][j]);
      }
    }
    __syncthreads();
  }
#pragma unroll
  for (int i = 0; i < TM_; i++) {
    int m = m0 + ty * TM_ + i;
    if (m >= M) break;
#pragma unroll
    for (int j = 0; j < 4; j++) {
      int n = n0 + (tx << 2) + j;
      C[(size_t)m * N + n] = acc[i][j] + bias[n];
    }
  }
}

// ------------- K5b: double-buffered dual GEMM (K multiple of 32, >=64) ----
template<int GM_, int TM_>
__global__ __launch_bounds__(256) void k_gemm_dual_db(
    const float* __restrict__ A,
    const float* __restrict__ W0, const float* __restrict__ b0,
    const float* __restrict__ W1, const float* __restrict__ b1,
    float* __restrict__ C0, float* __restrict__ C1,
    int M, int K, int N) {
  int nc = blockIdx.x * GN;
  const float* W    = (nc < N) ? W0 : W1;
  const float* bias = (nc < N) ? b0 : b1;
  float*       C    = (nc < N) ? C0 : C1;
  int n0 = (nc < N) ? nc : nc - N;
  int m0 = blockIdx.y * GM_;

  __shared__ float a_s[2][GK][GM_];
  __shared__ float b_s[2][GK][GN + 4];
  int t = threadIdx.x;
  int tx = t & 15, ty = t >> 4;
  constexpr int EPT = GM_ * GK / 256;   // 8 for GM=64
  constexpr int NF4 = EPT / 4;          // 2
  int ms = t & (GM_ - 1);
  int kq = (t / GM_) * EPT;
  int gm = m0 + ms;
  int kb = t >> 3;
  int n8 = (t & 7) * 8;
  const float* arow = A + (size_t)gm * K;

  float4 ra[NF4];
  float4 rb0, rb1;

  auto LOAD = [&](int kt) {
#pragma unroll
    for (int r = 0; r < NF4; r++)
      ra[r] = (gm < M) ? *(const float4*)(arow + kt + kq + 4 * r)
                       : make_float4(0.f, 0.f, 0.f, 0.f);
    const float* wp = W + (size_t)(kt + kb) * N + n0 + n8;
    rb0 = *(const float4*)(wp);
    rb1 = *(const float4*)(wp + 4);
  };
  auto STORE = [&](int buf) {
#pragma unroll
    for (int r = 0; r < NF4; r++) {
      a_s[buf][kq + 4 * r + 0][ms] = ra[r].x;
      a_s[buf][kq + 4 * r + 1][ms] = ra[r].y;
      a_s[buf][kq + 4 * r + 2][ms] = ra[r].z;
      a_s[buf][kq + 4 * r + 3][ms] = ra[r].w;
    }
    b_s[buf][kb][n8 + 0] = rb0.x; b_s[buf][kb][n8 + 1] = rb0.y;
    b_s[buf][kb][n8 + 2] = rb0.z; b_s[buf][kb][n8 + 3] = rb0.w;
    b_s[buf][kb][n8 + 4] = rb1.x; b_s[buf][kb][n8 + 5] = rb1.y;
    b_s[buf][kb][n8 + 6] = rb1.z; b_s[buf][kb][n8 + 7] = rb1.w;
  };

  float acc[TM_][4];
#pragma unroll
  for (int i = 0; i < TM_; i++)
#pragma unroll
    for (int j = 0; j < 4; j++) acc[i][j] = 0.f;

  auto COMPUTE = [&](int buf) {
#pragma unroll
    for (int kk = 0; kk < GK; kk++) {
      float4 bv = *(const float4*)(&b_s[buf][kk][tx << 2]);
      float bn_[4] = {bv.x, bv.y, bv.z, bv.w};
#pragma unroll
      for (int r = 0; r < TM_ / 4; r++) {
        float4 av = *(const float4*)(&a_s[buf][kk][ty * TM_ + 4 * r]);
        float am[4] = {av.x, av.y, av.z, av.w};
#pragma unroll
        for (int i = 0; i < 4; i++)
#pragma unroll
          for (int j = 0; j < 4; j++)
            acc[r * 4 + i][j] = fmaf(am[i], bn_[j], acc[r * 4 + i][j]);
      }
    }
  };

  int nt = K / GK;
  LOAD(0); STORE(0);
  __syncthreads();
  int cur = 0;
  for (int it = 1; it < nt; it++) {
    LOAD(it * GK);          // in flight during compute
    COMPUTE(cur);
    __syncthreads();        // everyone done reading cur
    STORE(cur ^ 1);
    __syncthreads();
    cur ^= 1;
  }
  COMPUTE(cur);

#pragma unroll
  for (int i = 0; i < TM_; i++) {
    int m = m0 + ty * TM_ + i;
    if (m >= M) break;
#pragma unroll
    for (int j = 0; j < 4; j++) {
      int n = n0 + (tx << 2) + j;
      C[(size_t)m * N + n] = acc[i][j] + bias[n];
    }
  }
}

// ------------- K6: fused GATv2 scores + softmax + aggregate + gelu --------
// 2 targets per block, 512 threads, grid 58 x 8 (~1.8 blocks/CU).
// alpha packed [h][j][2] for float2 broadcast in phase 3.
template<int HH_, int DD_>
__global__ __launch_bounds__(512) void k_attn_aggr(
    const float* __restrict__ xl, const float* __restrict__ xr,
    const float* __restrict__ adj, const float* __restrict__ att,
    const float* __restrict__ bias, float* __restrict__ hout, int selfloop) {
  constexpr int HD = HH_ * DD_;
  __shared__ float xr_lds[2][HD];
  __shared__ float att_lds[HD];
  __shared__ __align__(16) float e_lds[HH_][128][2];
  __shared__ float maskf[2][128];
  int i0 = blockIdx.x * 2, b = blockIdx.y;
  int t = threadIdx.x;

  for (int idx = t; idx < HD; idx += 512) {
    att_lds[idx] = att[idx];
    xr_lds[0][idx] = xr[(size_t)(b * NN + i0) * HD + idx];
    xr_lds[1][idx] = xr[(size_t)(b * NN + i0 + 1) * HD + idx];
  }
  if (t < 128) {
#pragma unroll
    for (int ti = 0; ti < 2; ti++) {
      int i = i0 + ti;
      bool mj = (t < NN) && ((adj[(size_t)(b * NN + t) * NN + i] > 0.5f) ||
                             (selfloop && (t == i)));
      maskf[ti][t] = mj ? 1.f : 0.f;
    }
  }
  __syncthreads();

  // ---- phase 1: raw scores e[ti][h][j] ----
  int slice = t >> 7;         // 0..3
  int j = t & 127;
  bool valid = (j < NN);
  const float* xlj = xl + (size_t)(b * NN + (valid ? j : 0)) * HD;
  if constexpr (HH_ >= 4) {
    constexpr int HQ = HH_ / 4;
#pragma unroll
    for (int hh = 0; hh < HQ; hh++) {
      int h = slice * HQ + hh;
      int base = h * DD_;
      float a0 = 0.f, a1 = 0.f;
      for (int o = 0; o < DD_; o += 4) {
        float4 v  = *(const float4*)(xlj + base + o);
        float4 af = *(const float4*)(att_lds + base + o);
        float4 r0 = *(const float4*)(&xr_lds[0][base + o]);
        float4 r1 = *(const float4*)(&xr_lds[1][base + o]);
        a0 = fmaf(af.x, lrelu(r0.x + v.x), a0);
        a0 = fmaf(af.y, lrelu(r0.y + v.y), a0);
        a0 = fmaf(af.z, lrelu(r0.z + v.z), a0);
        a0 = fmaf(af.w, lrelu(r0.w + v.w), a0);
        a1 = fmaf(af.x, lrelu(r1.x + v.x), a1);
        a1 = fmaf(af.y, lrelu(r1.y + v.y), a1);
        a1 = fmaf(af.z, lrelu(r1.z + v.z), a1);
        a1 = fmaf(af.w, lrelu(r1.w + v.w), a1);
      }
      if (valid) { e_lds[h][j][0] = a0; e_lds[h][j][1] = a1; }
    }
    __syncthreads();
  } else {
    // HH==1: exact 2-half split (slices 2,3 idle in compute)
    constexpr int DH = DD_ / 2;
    float a0 = 0.f, a1 = 0.f;
    if (slice < 2) {
      int base = slice * DH;
      for (int o = 0; o < DH; o += 4) {
        float4 v  = *(const float4*)(xlj + base + o);
        float4 af = *(const float4*)(att_lds + base + o);
        float4 r0 = *(const float4*)(&xr_lds[0][base + o]);
        float4 r1 = *(const float4*)(&xr_lds[1][base + o]);
        a0 = fmaf(af.x, lrelu(r0.x + v.x), a0);
        a0 = fmaf(af.y, lrelu(r0.y + v.y), a0);
        a0 = fmaf(af.z, lrelu(r0.z + v.z), a0);
        a0 = fmaf(af.w, lrelu(r0.w + v.w), a0);
        a1 = fmaf(af.x, lrelu(r1.x + v.x), a1);
        a1 = fmaf(af.y, lrelu(r1.y + v.y), a1);
        a1 = fmaf(af.z, lrelu(r1.z + v.z), a1);
        a1 = fmaf(af.w, lrelu(r1.w + v.w), a1);
      }
    }
    if (slice == 0 && valid) { e_lds[0][j][0] = a0; e_lds[0][j][1] = a1; }
    __syncthreads();
    if (slice == 1 && valid) { e_lds[0][j][0] += a0; e_lds[0][j][1] += a1; }
    __syncthreads();
  }

  // ---- phase 2: masked softmax; wave w owns (ti,h) pairs w, w+8, ... ----
  {
    int w = t >> 6, lane = t & 63;
    for (int fh = w; fh < 2 * HH_; fh += 8) {
      int ti = fh / HH_, h = fh - ti * HH_;
      float mk0 = maskf[ti][lane], mk1 = maskf[ti][lane + 64];
      float e0 = e_lds[h][lane][ti], e1 = e_lds[h][lane + 64][ti];
      float v = fmaxf(mk0 != 0.f ? e0 : -3.0e38f,
                      mk1 != 0.f ? e1 : -3.0e38f);
#pragma unroll
      for (int o = 32; o; o >>= 1) v = fmaxf(v, __shfl_xor(v, o, 64));
      float p0 = (mk0 != 0.f) ? expf(e0 - v) : 0.f;
      float p1 = (mk1 != 0.f) ? expf(e1 - v) : 0.f;
      float s = p0 + p1;
#pragma unroll
      for (int o = 32; o; o >>= 1) s += __shfl_xor(s, o, 64);
      float inv = 1.0f / fmaxf(s, 1e-16f);
      e_lds[h][lane][ti]      = p0 * inv;
      e_lds[h][lane + 64][ti] = p1 * inv;
    }
  }
  __syncthreads();

  // ---- phase 3: out[ti][c] = sum_j alpha[ti][h(c)][j] * xl[b,j,c] ----
  constexpr int CITER = HD / 512;
  const float* xb = xl + (size_t)b * NN * HD;
  float* hb = hout + (size_t)(b * NN + i0) * HD;
#pragma unroll
  for (int it = 0; it < CITER; it++) {
    int c = t + (it << 9);
    int h = c / DD_;
    const float* xp = xb + c;
    float a0 = 0.f, a1 = 0.f;
#pragma unroll 4
    for (int jj = 0; jj < NN; jj++) {
      float xv = xp[(size_t)jj * HD];
      float2 al = *(const float2*)(&e_lds[h][jj][0]);   // wave-uniform broadcast
      a0 = fmaf(al.x, xv, a0);
      a1 = fmaf(al.y, xv, a1);
    }
    float bv = bias[c];
    hb[c]      = gelu_f(a0 + bv);
    hb[HD + c] = gelu_f(a1 + bv);
  }
}

// ------------- K7: mean-pool + classifier ---------------------------------
__global__ __launch_bounds__(256) void k_classifier(
    const float* __restrict__ hfin,   // [8*116][512]
    const float* __restrict__ Wc1, const float* __restrict__ bc1,
    const float* __restrict__ bng, const float* __restrict__ bnb,
    const float* __restrict__ Wc2, const float* __restrict__ bc2,
    float* __restrict__ out) {
  __shared__ float pooled[512];
  __shared__ float cls[256];
  int b = blockIdx.x;
  int t = threadIdx.x;
#pragma unroll
  for (int r = 0; r < 2; r++) {
    int c = t + (r << 8);
    float s = 0.f;
    for (int i = 0; i < NN; i++) s += hfin[(size_t)(b * NN + i) * 512 + c];
    pooled[c] = s / (float)NN;
  }
  __syncthreads();
  {
    int n = t;
    float acc = bc1[n];
#pragma unroll 8
    for (int k = 0; k < 512; k++)
      acc = fmaf(pooled[k], Wc1[k * 256 + n], acc);
    float c = acc * (1.0f / sqrtf(1.0f + 1e-5f)) * bng[n] + bnb[n];
    cls[n] = gelu_f(c);
  }
  __syncthreads();
  if (t < 128) {
    int jj = t >> 6, lane = t & 63;
    float s = 0.f;
#pragma unroll
    for (int w = 0; w < 4; w++) {
      int k = lane + (w << 6);
      s += cls[k] * Wc2[k * 2 + jj];
    }
#pragma unroll
    for (int o = 32; o; o >>= 1) s += __shfl_xor(s, o, 64);
    if (lane == 0) out[b * 2 + jj] = s + bc2[jj];
  }
}

// --------------------------------------------------------------------------
extern "C" void kernel_launch(void* const* d_in, const int* in_sizes, int n_in,
                              void* d_out, int out_size, void* d_ws, size_t ws_size,
                              hipStream_t stream) {
  const float* x    = (const float*)d_in[0];
  const float* Wgb  = (const float*)d_in[1];
  const float* bgb  = (const float*)d_in[2];
  const float* feW1 = (const float*)d_in[3];
  const float* feb1 = (const float*)d_in[4];
  const float* feW2 = (const float*)d_in[5];
  const float* feb2 = (const float*)d_in[6];
  const float* lng  = (const float*)d_in[7];
  const float* lnb  = (const float*)d_in[8];
  const float* Wl[3]   = {(const float*)d_in[9],  (const float*)d_in[15], (const float*)d_in[21]};
  const float* bl[3]   = {(const float*)d_in[10], (const float*)d_in[16], (const float*)d_in[22]};
  const float* Wr[3]   = {(const float*)d_in[11], (const float*)d_in[17], (const float*)d_in[23]};
  const float* br[3]   = {(const float*)d_in[12], (const float*)d_in[18], (const float*)d_in[24]};
  const float* att[3]  = {(const float*)d_in[13], (const float*)d_in[19], (const float*)d_in[25]};
  const float* bias[3] = {(const float*)d_in[14], (const float*)d_in[20], (const float*)d_in[26]};
  const float* Wc1 = (const float*)d_in[27];
  const float* bc1 = (const float*)d_in[28];
  const float* bng = (const float*)d_in[29];
  const float* bnb = (const float*)d_in[30];
  const float* Wc2 = (const float*)d_in[31];
  const float* bc2 = (const float*)d_in[32];

  float* ws = (float*)d_ws;
  float* adj = ws + 53376;       // 107,648 floats
  float* scratch = ws + 161024;  // overlay region
  float* partial = scratch;            // 64*8*13456 = 6,889,472 (dead after K3)
  float* hA      = scratch;            // 928*1024
  float* hB      = hA + 950272;
  float* xlbuf   = hB + 950272;
  float* xrbuf   = xlbuf + 950272;

  k_gemm_big<<<dim3(14, KCHUNK), 256, 0, stream>>>(x, Wgb, partial);
  k_reduce_sigmoid<<<dim3((NB * NN2 + 255) / 256), 256, 0, stream>>>(partial, bgb, adj);
  k_stats<<<dim3(NB), 128, 0, stream>>>(adj, feW1, feb1, feW2, feb2, lng, lnb, hA);

  dim3 ab(NN / 2, NB);   // 58 x 8
  // ---- layer 0: 16 -> 8x128, no self loops ----
  k_gemm_dual_s<64, 4><<<dim3(2 * 1024 / GN, 15), 256, 0, stream>>>(
      hA, Wl[0], bl[0], Wr[0], br[0], xlbuf, xrbuf, 928, 16, 1024);
  k_attn_aggr<8, 128><<<ab, 512, 0, stream>>>(xlbuf, xrbuf, adj, att[0], bias[0], hB, 0);
  // ---- layer 1: 1024 -> 4x256, self loops ----
  k_gemm_dual_db<64, 4><<<dim3(2 * 1024 / GN, 15), 256, 0, stream>>>(
      hB, Wl[1], bl[1], Wr[1], br[1], xlbuf, xrbuf, 928, 1024, 1024);
  k_attn_aggr<4, 256><<<ab, 512, 0, stream>>>(xlbuf, xrbuf, adj, att[1], bias[1], hA, 1);
  // ---- layer 2: 1024 -> 1x512, self loops ----
  k_gemm_dual_db<64, 4><<<dim3(2 * 512 / GN, 15), 256, 0, stream>>>(
      hA, Wl[2], bl[2], Wr[2], br[2], xlbuf, xrbuf, 928, 1024, 512);
  k_attn_aggr<1, 512><<<ab, 512, 0, stream>>>(xlbuf, xrbuf, adj, att[2], bias[2], hB, 1);

  k_classifier<<<dim3(NB), 256, 0, stream>>>(hB, Wc1, bc1, bng, bnb, Wc2, bc2,
                                             (float*)d_out);
}